// Round 14
// baseline (257.849 us; speedup 1.0000x reference)
//
#include <hip/hip_runtime.h>

// Problem constants (match reference)
constexpr int U_N = 50000;
constexpr int V_N = 50000;
constexpr int E_N = 800000;   // == 16 * 50000
// dims: F=64, G=64, H=16; g: 144->128->64; f: 128->128->64

typedef float f32x4 __attribute__((ext_vector_type(4)));
typedef short bf16x8 __attribute__((ext_vector_type(8)));
typedef unsigned short u16x8 __attribute__((ext_vector_type(8)));

__device__ __forceinline__ float relu(float x) { return fmaxf(x, 0.f); }

// round-to-nearest-even fp32 -> bf16 bits
__device__ __forceinline__ unsigned short f2bf(float f) {
    unsigned u = __float_as_uint(f);
    unsigned rounding = 0x7FFFu + ((u >> 16) & 1u);
    return (unsigned short)((u + rounding) >> 16);
}
__device__ __forceinline__ float bf2f(unsigned short b) {
    return __uint_as_float(((unsigned)b) << 16);
}

constexpr int NB_HIST = (E_N + 255) / 256;   // 3125
constexpr int NB_PROJ = (U_N + 63) / 64;     // 782
constexpr int NBINS = U_N;                   // 50000
constexpr int NSCAN = (NBINS + 1023) / 1024; // 49

// Up/Vp rows are stored FRAGMENT-PERMUTED: element (col = ct*16 + hi*4 + j)
// lives at row offset hi*32 + ct*4 + j  (hi 0..3, ct 0..7, j 0..3).
// => each edge-kernel lane's 64B of gather data is CONTIGUOUS: 4 x 16B loads.

// ---------------------------------------------------------------------------
// proj via MFMA: P[row][*] = bf16(X[.][64]) @ bf16(W[64][128]), permuted store
// ---------------------------------------------------------------------------
__device__ __forceinline__ void proj_mfma(const float* __restrict__ X,
                                          const float* __restrict__ W,  // 64x128
                                          unsigned short* __restrict__ P,
                                          int N, int row0,
                                          unsigned short* sWf)
{
    const int tid = threadIdx.x;

    for (int idx = tid; idx < 64 * 128 / 4; idx += 256) {
        int k  = (idx * 4) >> 7;
        int n0 = (idx * 4) & 127;
        float4 w = *(const float4*)&W[k * 128 + n0];
        int ks = k >> 5, hi = (k & 31) >> 3, j = k & 7;
        float wv[4] = {w.x, w.y, w.z, w.w};
#pragma unroll
        for (int q = 0; q < 4; ++q) {
            int n = n0 + q, nt = n >> 4, lo = n & 15;
            sWf[((ks * 8 + nt) * 64 + hi * 16 + lo) * 8 + j] = f2bf(wv[q]);
        }
    }
    __syncthreads();

    const int wid = tid >> 6, lane = tid & 63;
    const int lo = lane & 15, hi = lane >> 4;
    const int row = row0 + wid * 16 + lo;
    const int rl = (row < N) ? row : (N - 1);

    bf16x8 a0, a1;
    {
        union { bf16x8 v; unsigned short s[8]; } ra, rb;
        float4 x0 = *(const float4*)&X[(size_t)rl * 64 + hi * 8];
        float4 x1 = *(const float4*)&X[(size_t)rl * 64 + hi * 8 + 4];
        ra.s[0] = f2bf(x0.x); ra.s[1] = f2bf(x0.y); ra.s[2] = f2bf(x0.z); ra.s[3] = f2bf(x0.w);
        ra.s[4] = f2bf(x1.x); ra.s[5] = f2bf(x1.y); ra.s[6] = f2bf(x1.z); ra.s[7] = f2bf(x1.w);
        float4 y0 = *(const float4*)&X[(size_t)rl * 64 + 32 + hi * 8];
        float4 y1 = *(const float4*)&X[(size_t)rl * 64 + 32 + hi * 8 + 4];
        rb.s[0] = f2bf(y0.x); rb.s[1] = f2bf(y0.y); rb.s[2] = f2bf(y0.z); rb.s[3] = f2bf(y0.w);
        rb.s[4] = f2bf(y1.x); rb.s[5] = f2bf(y1.y); rb.s[6] = f2bf(y1.z); rb.s[7] = f2bf(y1.w);
        a0 = ra.v; a1 = rb.v;
    }

    const int rbase = row0 + wid * 16 + hi * 4;
    const int ph = lo >> 2, pj = lo & 3;   // permuted-store decomposition of col
#pragma unroll
    for (int nt = 0; nt < 8; ++nt) {
        f32x4 acc;
#pragma unroll
        for (int r = 0; r < 4; ++r) acc[r] = 0.f;
        bf16x8 b0 = *(const bf16x8*)&sWf[((0 * 8 + nt) * 64 + lane) * 8];
        bf16x8 b1 = *(const bf16x8*)&sWf[((1 * 8 + nt) * 64 + lane) * 8];
        acc = __builtin_amdgcn_mfma_f32_16x16x32_bf16(a0, b0, acc, 0, 0, 0);
        acc = __builtin_amdgcn_mfma_f32_16x16x32_bf16(a1, b1, acc, 0, 0, 0);
#pragma unroll
        for (int r = 0; r < 4; ++r) {
            int gr = rbase + r;
            // col = nt*16 + lo  ->  permuted pos = (lo>>2)*32 + nt*4 + (lo&3)
            if (gr < N) P[(size_t)gr * 128 + ph * 32 + nt * 4 + pj] = f2bf(acc[r]);
        }
    }
}

// ---------------------------------------------------------------------------
// prep kernel: projU (MFMA), projV (MFMA), weight-pack, histogram.
// ---------------------------------------------------------------------------
__global__ __launch_bounds__(256) void prep_kernel(
    const int* __restrict__ idx_u, int* __restrict__ counts,
    const float* __restrict__ u, const float* __restrict__ v,
    const float* __restrict__ gw1, const float* __restrict__ gw2,
    const float* __restrict__ fw1, const float* __restrict__ fw2,
    unsigned short* __restrict__ Up, unsigned short* __restrict__ Vp,
    unsigned short* __restrict__ W2f, unsigned short* __restrict__ Wef,
    unsigned short* __restrict__ F1f, unsigned short* __restrict__ F2f)
{
    __shared__ unsigned short sWf[8192];   // proj branches only
    int b = blockIdx.x;

    if (b < NB_PROJ) {
        proj_mfma(u, gw1, Up, U_N, b * 64, sWf);
        return;
    }
    b -= NB_PROJ;
    if (b < NB_PROJ) {
        proj_mfma(v, gw1 + 64 * 128, Vp, V_N, b * 64, sWf);
        return;
    }
    b -= NB_PROJ;
    if (b == 0) {
        const int tid = threadIdx.x;
        // W2f (edge L2, gw2 128x64) and F2f (node L2, fw2 128x64): same layout
        for (int t = tid; t < 4 * 4 * 64 * 8; t += 256) {
            int j    = t & 7;
            int lane = (t >> 3) & 63;
            int nt   = (t >> 9) & 3;
            int ks   = t >> 11;
            int n = nt * 16 + (lane & 15);
            int k = ks * 32 + (lane >> 4) * 8 + j;
            W2f[t] = f2bf(gw2[k * 64 + n]);
            F2f[t] = f2bf(fw2[k * 64 + n]);
        }
        // Wef (edge L1 A-frags, We^T, K padded to 32)
        const float* gw1e = gw1 + 128 * 128;   // 16 x 128
        for (int t = tid; t < 8 * 64 * 8; t += 256) {
            int j    = t & 7;
            int lane = (t >> 3) & 63;
            int ct   = t >> 9;
            int c = ct * 16 + (lane & 15);
            int k = (lane >> 4) * 8 + j;
            Wef[t] = (k < 16) ? f2bf(gw1e[k * 128 + c]) : (unsigned short)0;
        }
        // F1f (node L1, fw1 128x128): ks 0..3, nt 0..7
        for (int t = tid; t < 4 * 8 * 64 * 8; t += 256) {
            int j    = t & 7;
            int lane = (t >> 3) & 63;
            int nt   = (t >> 9) & 7;
            int ks   = t >> 12;
            int n = nt * 16 + (lane & 15);
            int k = ks * 32 + (lane >> 4) * 8 + j;
            F1f[t] = f2bf(fw1[k * 128 + n]);
        }
        return;
    }
    b -= 1;
    // ---- histogram (key = iu) ----
    int e = b * 256 + threadIdx.x;
    if (e < E_N) atomicAdd(&counts[idx_u[e]], 1);
}

// ---------------------------------------------------------------------------
// multi-block exclusive scan of counts[0..NBINS): sums -> scan sums -> apply
// ---------------------------------------------------------------------------
__global__ __launch_bounds__(256) void scan_sums(const int* __restrict__ counts,
                                                 int* __restrict__ bsum)
{
    __shared__ int sred[256];
    const int tid = threadIdx.x;
    int base = blockIdx.x * 1024 + tid * 4;
    int s = 0;
    if (base + 3 < NBINS) {
        int4 c = *(const int4*)&counts[base];
        s = c.x + c.y + c.z + c.w;
    } else {
#pragma unroll
        for (int k = 0; k < 4; ++k) { int i = base + k; if (i < NBINS) s += counts[i]; }
    }
    sred[tid] = s;
    __syncthreads();
    for (int off = 128; off > 0; off >>= 1) {
        if (tid < off) sred[tid] += sred[tid + off];
        __syncthreads();
    }
    if (tid == 0) bsum[blockIdx.x] = sred[0];
}

__global__ __launch_bounds__(512) void scan_bsum(int* __restrict__ bsum)
{
    __shared__ int sScan[512];
    const int tid = threadIdx.x;
    int vIn = (tid < NSCAN) ? bsum[tid] : 0;
    sScan[tid] = vIn;
    __syncthreads();
    for (int off = 1; off < 512; off <<= 1) {
        int val = (tid >= off) ? sScan[tid - off] : 0;
        __syncthreads();
        sScan[tid] += val;
        __syncthreads();
    }
    if (tid < NSCAN) bsum[tid] = sScan[tid] - vIn;   // exclusive
}

__global__ __launch_bounds__(256) void scan_apply(int* __restrict__ counts,
                                                  const int* __restrict__ bsum)
{
    __shared__ int sScan[256];
    const int tid = threadIdx.x;
    int base = blockIdx.x * 1024 + tid * 4;
    int v0 = 0, v1 = 0, v2 = 0, v3 = 0;
    if (base + 3 < NBINS) {
        int4 c = *(const int4*)&counts[base];
        v0 = c.x; v1 = c.y; v2 = c.z; v3 = c.w;
    } else {
        if (base     < NBINS) v0 = counts[base];
        if (base + 1 < NBINS) v1 = counts[base + 1];
        if (base + 2 < NBINS) v2 = counts[base + 2];
        if (base + 3 < NBINS) v3 = counts[base + 3];
    }
    int tsum = v0 + v1 + v2 + v3;
    sScan[tid] = tsum;
    __syncthreads();
    for (int off = 1; off < 256; off <<= 1) {
        int val = (tid >= off) ? sScan[tid - off] : 0;
        __syncthreads();
        sScan[tid] += val;
        __syncthreads();
    }
    int excl = sScan[tid] - tsum + bsum[blockIdx.x];
    if (base     < NBINS) counts[base]     = excl;
    if (base + 1 < NBINS) counts[base + 1] = excl + v0;
    if (base + 2 < NBINS) counts[base + 2] = excl + v0 + v1;
    if (base + 3 < NBINS) counts[base + 3] = excl + v0 + v1 + v2;
}

// ---------------------------------------------------------------------------
// permute+gather: scatter edges into iu-sorted order, pre-gathering
// iuv packed indices + ev row as bf16.
// ---------------------------------------------------------------------------
__global__ __launch_bounds__(256) void permute_kernel(
    const int* __restrict__ idx_u, const int* __restrict__ idx_v,
    const float* __restrict__ ev, int* __restrict__ cursor,
    unsigned int* __restrict__ iuv_s, unsigned short* __restrict__ evs)
{
    int e = blockIdx.x * 256 + threadIdx.x;
    if (e >= E_N) return;
    int iu = idx_u[e];
    int iv = idx_v[e];
    int pos = atomicAdd(&cursor[iu], 1);
    iuv_s[pos] = (unsigned)iu | ((unsigned)iv << 16);

    const float* src = &ev[(size_t)e * 16];
    unsigned short* dst = &evs[(size_t)pos * 16];
#pragma unroll
    for (int q = 0; q < 4; ++q) {
        float4 a = *(const float4*)&src[q * 4];
        ushort4 o;
        o.x = f2bf(a.x); o.y = f2bf(a.y); o.z = f2bf(a.z); o.w = f2bf(a.w);
        *(ushort4*)&dst[q * 4] = o;
    }
}

// ---------------------------------------------------------------------------
// edge kernel: ONE WAVE per block (64 threads, 16 edges). All state is
// wave-local; LDS = 4.4 KB/block -> occupancy cap is the architectural
// 32 waves/CU (vs 20 at 256-thread blocks): 1.6x gather chains in flight.
// Same verified R13 dataflow (fragment-permuted Up/Vp, 4+4 x 16B gathers).
// ---------------------------------------------------------------------------
__global__ __launch_bounds__(64, 8) void edge_kernel(
    const unsigned short* __restrict__ Up,   // 50000 x 128 bf16, permuted rows
    const unsigned short* __restrict__ Vp,   // 50000 x 128 bf16, permuted rows
    const unsigned short* __restrict__ evs,  // E x 16 bf16, sorted
    const unsigned int* __restrict__ iuv_s,  // E packed (iu | iv<<16), sorted
    const unsigned short* __restrict__ Wef,  // layer-1 A frags (We^T, K=32 pad)
    const float* __restrict__ gb1,
    const unsigned short* __restrict__ W2f,  // layer-2 B frags
    const float* __restrict__ gb2,
    float* __restrict__ agg)
{
    __shared__ unsigned short sH1[16 * 136];  // 4352 B; aliased as sH2 f32 [16][68]
    __shared__ int sIu[16];

    const int lane = threadIdx.x;             // one wave
    const int lo = lane & 15, hi = lane >> 4;
    const int g = blockIdx.x * 16 + lo;       // this lane's (sorted) edge

    const unsigned iuv = iuv_s[g];
    const int iu = (int)(iuv & 0xFFFFu);
    const int iv = (int)(iuv >> 16);
    if (hi == 0) sIu[lo] = iu;                // wave-local write

    // ---- register-prefetch the gathers: 4+4 contiguous 16B loads ----
    u16x8 upv[4], vpv[4];
#pragma unroll
    for (int ctp = 0; ctp < 4; ++ctp) {
        upv[ctp] = *(const u16x8*)&Up[(size_t)iu * 128 + hi * 32 + ctp * 8];
        vpv[ctp] = *(const u16x8*)&Vp[(size_t)iv * 128 + hi * 32 + ctp * 8];
    }

    // ---- layer 1 MFMA: B-frag = evs row (coalesced); A = Wef (L1-hot) ----
    bf16x8 bfrag;
    if (hi < 2) {
        bfrag = *(const bf16x8*)&evs[(size_t)g * 16 + hi * 8];
    } else {
        bfrag = (bf16x8)(short)0;             // K-pad 16->32
    }

    f32x4 acc[8];
#pragma unroll
    for (int ct = 0; ct < 8; ++ct) {
#pragma unroll
        for (int r = 0; r < 4; ++r) acc[ct][r] = 0.f;
        bf16x8 a = *(const bf16x8*)&Wef[(size_t)((ct * 64 + lane) * 8)];
        acc[ct] = __builtin_amdgcn_mfma_f32_16x16x32_bf16(a, bfrag, acc[ct], 0, 0, 0);
    }

    // epilogue: h1 = relu(acc + b1 + Up[iu] + Vp[iv]) -> bf16 LDS (wave-local)
    // upv[ctp]/vpv[ctp] hold cts {2ctp, 2ctp+1}: elems 0-3 and 4-7.
#pragma unroll
    for (int ctp = 0; ctp < 4; ++ctp) {
        u16x8 uv = upv[ctp], vv = vpv[ctp];
#pragma unroll
        for (int half = 0; half < 2; ++half) {
            const int ct = ctp * 2 + half;
            const int c0 = ct * 16 + hi * 4;
            float4 b1 = *(const float4*)&gb1[c0];
            ushort4 h;
            h.x = f2bf(relu(acc[ct][0] + b1.x + bf2f(uv[half * 4 + 0]) + bf2f(vv[half * 4 + 0])));
            h.y = f2bf(relu(acc[ct][1] + b1.y + bf2f(uv[half * 4 + 1]) + bf2f(vv[half * 4 + 1])));
            h.z = f2bf(relu(acc[ct][2] + b1.z + bf2f(uv[half * 4 + 2]) + bf2f(vv[half * 4 + 2])));
            h.w = f2bf(relu(acc[ct][3] + b1.w + bf2f(uv[half * 4 + 3]) + bf2f(vv[half * 4 + 3])));
            *(ushort4*)&sH1[lo * 136 + c0] = h;
        }
    }
    // intra-wave ushort write->read on same array: compiler-ordered, no barrier

    // ---- layer 2 via MFMA: wave reads its own 16 rows of sH1 ----
    f32x4 accm[4];
#pragma unroll
    for (int nt = 0; nt < 4; ++nt)
#pragma unroll
        for (int r = 0; r < 4; ++r) accm[nt][r] = 0.f;

#pragma unroll
    for (int ks = 0; ks < 4; ++ks) {
        bf16x8 a = *(const bf16x8*)&sH1[lo * 136 + ks * 32 + hi * 8];
#pragma unroll
        for (int nt = 0; nt < 4; ++nt) {
            bf16x8 b = *(const bf16x8*)&W2f[(size_t)(((ks * 4 + nt) * 64 + lane) * 8)];
            accm[nt] = __builtin_amdgcn_mfma_f32_16x16x32_bf16(a, b, accm[nt], 0, 0, 0);
        }
    }
    __syncthreads();   // alias (ushort->float) boundary (single wave: cheap)

    float* sH2 = (float*)sH1;   // [16][68] fp32; same byte range
#pragma unroll
    for (int nt = 0; nt < 4; ++nt) {
        int col = nt * 16 + lo;
        float b2v = gb2[col];
        int erow = hi * 4;
#pragma unroll
        for (int r = 0; r < 4; ++r)
            sH2[(erow + r) * 68 + col] = relu(accm[nt][r] + b2v);
    }
    // reduction reads this wave's rows (float->float, intra-wave): no barrier

    // ---- segmented reduction over this wave's 16 sorted edges ----
    {
        const int c = lane;           // output column
        int   iu_cur = sIu[0];
        float running = 0.f;
#pragma unroll
        for (int k = 0; k < 16; ++k) {
            int iu2 = sIu[k];
            if (iu2 != iu_cur) {
                atomicAdd(&agg[(size_t)iu_cur * 64 + c], running);
                running = 0.f;
                iu_cur = iu2;
            }
            running += sH2[k * 68 + c];
        }
        atomicAdd(&agg[(size_t)iu_cur * 64 + c], running);
    }
}

// ---------------------------------------------------------------------------
// node kernel via MFMA: out = relu(relu([u,agg] @ fw1 + fb1) @ fw2 + fb2)
// ---------------------------------------------------------------------------
__global__ __launch_bounds__(256) void node_kernel(
    const float* __restrict__ u, const float* __restrict__ agg,
    const unsigned short* __restrict__ F1f, const float* __restrict__ fb1,
    const unsigned short* __restrict__ F2f, const float* __restrict__ fb2,
    float* __restrict__ out, int N)
{
    __shared__ unsigned short sY[64 * 136];   // y bf16, wave-local rows
    const int tid = threadIdx.x;
    const int wid = tid >> 6, lane = tid & 63;
    const int lo = lane & 15, hi = lane >> 4;
    const int row0 = blockIdx.x * 64;
    const int row = row0 + wid * 16 + lo;
    const int rl = (row < N) ? row : (N - 1);

    bf16x8 a0, a1, a2, a3;
    {
        union { bf16x8 v; unsigned short s[8]; } r0_, r1_, r2_, r3_;
        float4 x0 = *(const float4*)&u[(size_t)rl * 64 + hi * 8];
        float4 x1 = *(const float4*)&u[(size_t)rl * 64 + hi * 8 + 4];
        float4 x2 = *(const float4*)&u[(size_t)rl * 64 + 32 + hi * 8];
        float4 x3 = *(const float4*)&u[(size_t)rl * 64 + 32 + hi * 8 + 4];
        float4 g0 = *(const float4*)&agg[(size_t)rl * 64 + hi * 8];
        float4 g1 = *(const float4*)&agg[(size_t)rl * 64 + hi * 8 + 4];
        float4 g2 = *(const float4*)&agg[(size_t)rl * 64 + 32 + hi * 8];
        float4 g3 = *(const float4*)&agg[(size_t)rl * 64 + 32 + hi * 8 + 4];
        r0_.s[0] = f2bf(x0.x); r0_.s[1] = f2bf(x0.y); r0_.s[2] = f2bf(x0.z); r0_.s[3] = f2bf(x0.w);
        r0_.s[4] = f2bf(x1.x); r0_.s[5] = f2bf(x1.y); r0_.s[6] = f2bf(x1.z); r0_.s[7] = f2bf(x1.w);
        r1_.s[0] = f2bf(x2.x); r1_.s[1] = f2bf(x2.y); r1_.s[2] = f2bf(x2.z); r1_.s[3] = f2bf(x2.w);
        r1_.s[4] = f2bf(x3.x); r1_.s[5] = f2bf(x3.y); r1_.s[6] = f2bf(x3.z); r1_.s[7] = f2bf(x3.w);
        r2_.s[0] = f2bf(g0.x); r2_.s[1] = f2bf(g0.y); r2_.s[2] = f2bf(g0.z); r2_.s[3] = f2bf(g0.w);
        r2_.s[4] = f2bf(g1.x); r2_.s[5] = f2bf(g1.y); r2_.s[6] = f2bf(g1.z); r2_.s[7] = f2bf(g1.w);
        r3_.s[0] = f2bf(g2.x); r3_.s[1] = f2bf(g2.y); r3_.s[2] = f2bf(g2.z); r3_.s[3] = f2bf(g2.w);
        r3_.s[4] = f2bf(g3.x); r3_.s[5] = f2bf(g3.y); r3_.s[6] = f2bf(g3.z); r3_.s[7] = f2bf(g3.w);
        a0 = r0_.v; a1 = r1_.v; a2 = r2_.v; a3 = r3_.v;
    }

    // ---- layer 1: y = relu(x @ fw1 + fb1), 32 MFMAs/wave ----
#pragma unroll
    for (int nt = 0; nt < 8; ++nt) {
        f32x4 acc;
#pragma unroll
        for (int r = 0; r < 4; ++r) acc[r] = 0.f;
        bf16x8 b0 = *(const bf16x8*)&F1f[(size_t)(((0 * 8 + nt) * 64 + lane) * 8)];
        bf16x8 b1 = *(const bf16x8*)&F1f[(size_t)(((1 * 8 + nt) * 64 + lane) * 8)];
        bf16x8 b2 = *(const bf16x8*)&F1f[(size_t)(((2 * 8 + nt) * 64 + lane) * 8)];
        bf16x8 b3 = *(const bf16x8*)&F1f[(size_t)(((3 * 8 + nt) * 64 + lane) * 8)];
        acc = __builtin_amdgcn_mfma_f32_16x16x32_bf16(a0, b0, acc, 0, 0, 0);
        acc = __builtin_amdgcn_mfma_f32_16x16x32_bf16(a1, b1, acc, 0, 0, 0);
        acc = __builtin_amdgcn_mfma_f32_16x16x32_bf16(a2, b2, acc, 0, 0, 0);
        acc = __builtin_amdgcn_mfma_f32_16x16x32_bf16(a3, b3, acc, 0, 0, 0);
        int col = nt * 16 + lo;
        float b1v = fb1[col];
        int rbase = wid * 16 + hi * 4;
#pragma unroll
        for (int r = 0; r < 4; ++r)
            sY[(rbase + r) * 136 + col] = f2bf(relu(acc[r] + b1v));
    }

    // ---- layer 2: out = relu(y @ fw2 + fb2), 16 MFMAs/wave ----
    bf16x8 ya0 = *(const bf16x8*)&sY[(wid * 16 + lo) * 136 + 0 * 32 + hi * 8];
    bf16x8 ya1 = *(const bf16x8*)&sY[(wid * 16 + lo) * 136 + 1 * 32 + hi * 8];
    bf16x8 ya2 = *(const bf16x8*)&sY[(wid * 16 + lo) * 136 + 2 * 32 + hi * 8];
    bf16x8 ya3 = *(const bf16x8*)&sY[(wid * 16 + lo) * 136 + 3 * 32 + hi * 8];
#pragma unroll
    for (int nt = 0; nt < 4; ++nt) {
        f32x4 acc;
#pragma unroll
        for (int r = 0; r < 4; ++r) acc[r] = 0.f;
        bf16x8 b0 = *(const bf16x8*)&F2f[(size_t)(((0 * 4 + nt) * 64 + lane) * 8)];
        bf16x8 b1 = *(const bf16x8*)&F2f[(size_t)(((1 * 4 + nt) * 64 + lane) * 8)];
        bf16x8 b2 = *(const bf16x8*)&F2f[(size_t)(((2 * 4 + nt) * 64 + lane) * 8)];
        bf16x8 b3 = *(const bf16x8*)&F2f[(size_t)(((3 * 4 + nt) * 64 + lane) * 8)];
        acc = __builtin_amdgcn_mfma_f32_16x16x32_bf16(ya0, b0, acc, 0, 0, 0);
        acc = __builtin_amdgcn_mfma_f32_16x16x32_bf16(ya1, b1, acc, 0, 0, 0);
        acc = __builtin_amdgcn_mfma_f32_16x16x32_bf16(ya2, b2, acc, 0, 0, 0);
        acc = __builtin_amdgcn_mfma_f32_16x16x32_bf16(ya3, b3, acc, 0, 0, 0);
        int col = nt * 16 + lo;
        float b2v = fb2[col];
#pragma unroll
        for (int r = 0; r < 4; ++r) {
            int gr = row0 + wid * 16 + hi * 4 + r;
            if (gr < N) out[(size_t)gr * 64 + col] = relu(acc[r] + b2v);
        }
    }
}

// ---------------------------------------------------------------------------
extern "C" void kernel_launch(void* const* d_in, const int* in_sizes, int n_in,
                              void* d_out, int out_size, void* d_ws, size_t ws_size,
                              hipStream_t stream)
{
    const float* u   = (const float*)d_in[0];
    const float* v   = (const float*)d_in[1];
    const float* ev  = (const float*)d_in[2];
    const int*   eiv = (const int*)d_in[3];
    const int*   eiu = (const int*)d_in[4];
    const float* gw1 = (const float*)d_in[5];   // 144 x 128
    const float* gb1 = (const float*)d_in[6];   // 128
    const float* gw2 = (const float*)d_in[7];   // 128 x 64
    const float* gb2 = (const float*)d_in[8];   // 64
    const float* fw1 = (const float*)d_in[9];   // 128 x 128
    const float* fb1 = (const float*)d_in[10];  // 128
    const float* fw2 = (const float*)d_in[11];  // 128 x 64
    const float* fb2 = (const float*)d_in[12];  // 64
    float* out = (float*)d_out;

    // workspace layout (agg and counts adjacent -> single memset); ~67.5 MB
    unsigned short* Up     = (unsigned short*)d_ws;                 // 50000x128 bf16
    unsigned short* Vp     = Up + (size_t)U_N * 128;                // 50000x128 bf16
    unsigned short* evs    = Vp + (size_t)V_N * 128;                // E x 16 bf16
    float*          agg    = (float*)(evs + (size_t)E_N * 16);      // 50000x64 f32
    int*            counts = (int*)(agg + (size_t)U_N * 64);        // NBINS (= cursor)
    unsigned int*   iuv_s  = (unsigned int*)(counts + NBINS);       // 800000
    unsigned short* W2f    = (unsigned short*)(iuv_s + E_N);        // 8192 bf16
    unsigned short* Wef    = W2f + 8192;                            // 4096 bf16
    unsigned short* F1f    = Wef + 4096;                            // 16384 bf16
    unsigned short* F2f    = F1f + 16384;                           // 8192 bf16
    int*            bsum   = (int*)(F2f + 8192);                    // NSCAN ints

    // one memset covers agg (zero init) + counts (hist init)
    hipMemsetAsync(agg, 0, ((size_t)U_N * 64 + NBINS) * sizeof(float), stream);

    dim3 blk(256);
    prep_kernel<<<dim3(2 * NB_PROJ + 1 + NB_HIST), blk, 0, stream>>>(
        eiu, counts, u, v, gw1, gw2, fw1, fw2, Up, Vp, W2f, Wef, F1f, F2f);
    scan_sums<<<dim3(NSCAN), blk, 0, stream>>>(counts, bsum);
    scan_bsum<<<dim3(1), dim3(512), 0, stream>>>(bsum);
    scan_apply<<<dim3(NSCAN), blk, 0, stream>>>(counts, bsum);
    permute_kernel<<<dim3(NB_HIST), blk, 0, stream>>>(
        eiu, eiv, ev, counts, iuv_s, evs);

    edge_kernel<<<dim3(E_N / 16), dim3(64), 0, stream>>>(
        Up, Vp, evs, iuv_s, Wef, gb1, W2f, gb2, agg);
    node_kernel<<<dim3((U_N + 63) / 64), blk, 0, stream>>>(
        u, agg, F1f, fb1, F2f, fb2, out, U_N);
}

// Round 15
// 229.111 us; speedup vs baseline: 1.1254x; 1.1254x over previous
//
#include <hip/hip_runtime.h>

// Problem constants (match reference)
constexpr int U_N = 50000;
constexpr int V_N = 50000;
constexpr int E_N = 800000;   // == 64 * 12500
// dims: F=64, G=64, H=16; g: 144->128->64; f: 128->128->64

typedef float f32x4 __attribute__((ext_vector_type(4)));
typedef short bf16x8 __attribute__((ext_vector_type(8)));
typedef unsigned short u16x8 __attribute__((ext_vector_type(8)));

__device__ __forceinline__ float relu(float x) { return fmaxf(x, 0.f); }

// round-to-nearest-even fp32 -> bf16 bits
__device__ __forceinline__ unsigned short f2bf(float f) {
    unsigned u = __float_as_uint(f);
    unsigned rounding = 0x7FFFu + ((u >> 16) & 1u);
    return (unsigned short)((u + rounding) >> 16);
}
__device__ __forceinline__ float bf2f(unsigned short b) {
    return __uint_as_float(((unsigned)b) << 16);
}

constexpr int NB_HIST = (E_N + 255) / 256;   // 3125
constexpr int NB_PROJ = (U_N + 63) / 64;     // 782
constexpr int NBINS = U_N;                   // 50000
constexpr int NSCAN = (NBINS + 1023) / 1024; // 49

// Up/Vp rows are stored FRAGMENT-PERMUTED: element (col = ct*16 + hi*4 + j)
// lives at row offset hi*32 + ct*4 + j  (hi 0..3, ct 0..7, j 0..3).
// => each edge-kernel lane's 64B of gather data is CONTIGUOUS: 4 x 16B loads.

// ---------------------------------------------------------------------------
// proj via MFMA: P[row][*] = bf16(X[.][64]) @ bf16(W[64][128]), permuted store
// ---------------------------------------------------------------------------
__device__ __forceinline__ void proj_mfma(const float* __restrict__ X,
                                          const float* __restrict__ W,  // 64x128
                                          unsigned short* __restrict__ P,
                                          int N, int row0,
                                          unsigned short* sWf)
{
    const int tid = threadIdx.x;

    for (int idx = tid; idx < 64 * 128 / 4; idx += 256) {
        int k  = (idx * 4) >> 7;
        int n0 = (idx * 4) & 127;
        float4 w = *(const float4*)&W[k * 128 + n0];
        int ks = k >> 5, hi = (k & 31) >> 3, j = k & 7;
        float wv[4] = {w.x, w.y, w.z, w.w};
#pragma unroll
        for (int q = 0; q < 4; ++q) {
            int n = n0 + q, nt = n >> 4, lo = n & 15;
            sWf[((ks * 8 + nt) * 64 + hi * 16 + lo) * 8 + j] = f2bf(wv[q]);
        }
    }
    __syncthreads();

    const int wid = tid >> 6, lane = tid & 63;
    const int lo = lane & 15, hi = lane >> 4;
    const int row = row0 + wid * 16 + lo;
    const int rl = (row < N) ? row : (N - 1);

    bf16x8 a0, a1;
    {
        union { bf16x8 v; unsigned short s[8]; } ra, rb;
        float4 x0 = *(const float4*)&X[(size_t)rl * 64 + hi * 8];
        float4 x1 = *(const float4*)&X[(size_t)rl * 64 + hi * 8 + 4];
        ra.s[0] = f2bf(x0.x); ra.s[1] = f2bf(x0.y); ra.s[2] = f2bf(x0.z); ra.s[3] = f2bf(x0.w);
        ra.s[4] = f2bf(x1.x); ra.s[5] = f2bf(x1.y); ra.s[6] = f2bf(x1.z); ra.s[7] = f2bf(x1.w);
        float4 y0 = *(const float4*)&X[(size_t)rl * 64 + 32 + hi * 8];
        float4 y1 = *(const float4*)&X[(size_t)rl * 64 + 32 + hi * 8 + 4];
        rb.s[0] = f2bf(y0.x); rb.s[1] = f2bf(y0.y); rb.s[2] = f2bf(y0.z); rb.s[3] = f2bf(y0.w);
        rb.s[4] = f2bf(y1.x); rb.s[5] = f2bf(y1.y); rb.s[6] = f2bf(y1.z); rb.s[7] = f2bf(y1.w);
        a0 = ra.v; a1 = rb.v;
    }

    const int rbase = row0 + wid * 16 + hi * 4;
    const int ph = lo >> 2, pj = lo & 3;   // permuted-store decomposition of col
#pragma unroll
    for (int nt = 0; nt < 8; ++nt) {
        f32x4 acc;
#pragma unroll
        for (int r = 0; r < 4; ++r) acc[r] = 0.f;
        bf16x8 b0 = *(const bf16x8*)&sWf[((0 * 8 + nt) * 64 + lane) * 8];
        bf16x8 b1 = *(const bf16x8*)&sWf[((1 * 8 + nt) * 64 + lane) * 8];
        acc = __builtin_amdgcn_mfma_f32_16x16x32_bf16(a0, b0, acc, 0, 0, 0);
        acc = __builtin_amdgcn_mfma_f32_16x16x32_bf16(a1, b1, acc, 0, 0, 0);
#pragma unroll
        for (int r = 0; r < 4; ++r) {
            int gr = rbase + r;
            // col = nt*16 + lo  ->  permuted pos = (lo>>2)*32 + nt*4 + (lo&3)
            if (gr < N) P[(size_t)gr * 128 + ph * 32 + nt * 4 + pj] = f2bf(acc[r]);
        }
    }
}

// ---------------------------------------------------------------------------
// prep kernel: projU (MFMA), projV (MFMA), weight-pack, histogram.
// ---------------------------------------------------------------------------
__global__ __launch_bounds__(256) void prep_kernel(
    const int* __restrict__ idx_u, int* __restrict__ counts,
    const float* __restrict__ u, const float* __restrict__ v,
    const float* __restrict__ gw1, const float* __restrict__ gw2,
    const float* __restrict__ fw1, const float* __restrict__ fw2,
    unsigned short* __restrict__ Up, unsigned short* __restrict__ Vp,
    unsigned short* __restrict__ W2f, unsigned short* __restrict__ Wef,
    unsigned short* __restrict__ F1f, unsigned short* __restrict__ F2f)
{
    __shared__ unsigned short sWf[8192];   // proj branches only
    int b = blockIdx.x;

    if (b < NB_PROJ) {
        proj_mfma(u, gw1, Up, U_N, b * 64, sWf);
        return;
    }
    b -= NB_PROJ;
    if (b < NB_PROJ) {
        proj_mfma(v, gw1 + 64 * 128, Vp, V_N, b * 64, sWf);
        return;
    }
    b -= NB_PROJ;
    if (b == 0) {
        const int tid = threadIdx.x;
        // W2f (edge L2, gw2 128x64) and F2f (node L2, fw2 128x64): same layout
        for (int t = tid; t < 4 * 4 * 64 * 8; t += 256) {
            int j    = t & 7;
            int lane = (t >> 3) & 63;
            int nt   = (t >> 9) & 3;
            int ks   = t >> 11;
            int n = nt * 16 + (lane & 15);
            int k = ks * 32 + (lane >> 4) * 8 + j;
            W2f[t] = f2bf(gw2[k * 64 + n]);
            F2f[t] = f2bf(fw2[k * 64 + n]);
        }
        // Wef (edge L1 A-frags, We^T, K padded to 32)
        const float* gw1e = gw1 + 128 * 128;   // 16 x 128
        for (int t = tid; t < 8 * 64 * 8; t += 256) {
            int j    = t & 7;
            int lane = (t >> 3) & 63;
            int ct   = t >> 9;
            int c = ct * 16 + (lane & 15);
            int k = (lane >> 4) * 8 + j;
            Wef[t] = (k < 16) ? f2bf(gw1e[k * 128 + c]) : (unsigned short)0;
        }
        // F1f (node L1, fw1 128x128): ks 0..3, nt 0..7
        for (int t = tid; t < 4 * 8 * 64 * 8; t += 256) {
            int j    = t & 7;
            int lane = (t >> 3) & 63;
            int nt   = (t >> 9) & 7;
            int ks   = t >> 12;
            int n = nt * 16 + (lane & 15);
            int k = ks * 32 + (lane >> 4) * 8 + j;
            F1f[t] = f2bf(fw1[k * 128 + n]);
        }
        return;
    }
    b -= 1;
    // ---- histogram (key = iu) ----
    int e = b * 256 + threadIdx.x;
    if (e < E_N) atomicAdd(&counts[idx_u[e]], 1);
}

// ---------------------------------------------------------------------------
// multi-block exclusive scan of counts[0..NBINS): sums -> scan sums -> apply
// ---------------------------------------------------------------------------
__global__ __launch_bounds__(256) void scan_sums(const int* __restrict__ counts,
                                                 int* __restrict__ bsum)
{
    __shared__ int sred[256];
    const int tid = threadIdx.x;
    int base = blockIdx.x * 1024 + tid * 4;
    int s = 0;
    if (base + 3 < NBINS) {
        int4 c = *(const int4*)&counts[base];
        s = c.x + c.y + c.z + c.w;
    } else {
#pragma unroll
        for (int k = 0; k < 4; ++k) { int i = base + k; if (i < NBINS) s += counts[i]; }
    }
    sred[tid] = s;
    __syncthreads();
    for (int off = 128; off > 0; off >>= 1) {
        if (tid < off) sred[tid] += sred[tid + off];
        __syncthreads();
    }
    if (tid == 0) bsum[blockIdx.x] = sred[0];
}

__global__ __launch_bounds__(512) void scan_bsum(int* __restrict__ bsum)
{
    __shared__ int sScan[512];
    const int tid = threadIdx.x;
    int vIn = (tid < NSCAN) ? bsum[tid] : 0;
    sScan[tid] = vIn;
    __syncthreads();
    for (int off = 1; off < 512; off <<= 1) {
        int val = (tid >= off) ? sScan[tid - off] : 0;
        __syncthreads();
        sScan[tid] += val;
        __syncthreads();
    }
    if (tid < NSCAN) bsum[tid] = sScan[tid] - vIn;   // exclusive
}

__global__ __launch_bounds__(256) void scan_apply(int* __restrict__ counts,
                                                  const int* __restrict__ bsum)
{
    __shared__ int sScan[256];
    const int tid = threadIdx.x;
    int base = blockIdx.x * 1024 + tid * 4;
    int v0 = 0, v1 = 0, v2 = 0, v3 = 0;
    if (base + 3 < NBINS) {
        int4 c = *(const int4*)&counts[base];
        v0 = c.x; v1 = c.y; v2 = c.z; v3 = c.w;
    } else {
        if (base     < NBINS) v0 = counts[base];
        if (base + 1 < NBINS) v1 = counts[base + 1];
        if (base + 2 < NBINS) v2 = counts[base + 2];
        if (base + 3 < NBINS) v3 = counts[base + 3];
    }
    int tsum = v0 + v1 + v2 + v3;
    sScan[tid] = tsum;
    __syncthreads();
    for (int off = 1; off < 256; off <<= 1) {
        int val = (tid >= off) ? sScan[tid - off] : 0;
        __syncthreads();
        sScan[tid] += val;
        __syncthreads();
    }
    int excl = sScan[tid] - tsum + bsum[blockIdx.x];
    if (base     < NBINS) counts[base]     = excl;
    if (base + 1 < NBINS) counts[base + 1] = excl + v0;
    if (base + 2 < NBINS) counts[base + 2] = excl + v0 + v1;
    if (base + 3 < NBINS) counts[base + 3] = excl + v0 + v1 + v2;
}

// ---------------------------------------------------------------------------
// permute+gather: scatter edges into iu-sorted order, pre-gathering
// iuv packed indices + ev row as bf16 (two 16B stores per edge).
// ---------------------------------------------------------------------------
__global__ __launch_bounds__(256) void permute_kernel(
    const int* __restrict__ idx_u, const int* __restrict__ idx_v,
    const float* __restrict__ ev, int* __restrict__ cursor,
    unsigned int* __restrict__ iuv_s, unsigned short* __restrict__ evs)
{
    int e = blockIdx.x * 256 + threadIdx.x;
    if (e >= E_N) return;
    int iu = idx_u[e];
    int iv = idx_v[e];
    int pos = atomicAdd(&cursor[iu], 1);
    iuv_s[pos] = (unsigned)iu | ((unsigned)iv << 16);

    const float* src = &ev[(size_t)e * 16];
    unsigned short* dst = &evs[(size_t)pos * 16];
#pragma unroll
    for (int q = 0; q < 2; ++q) {
        float4 a = *(const float4*)&src[q * 8];
        float4 b = *(const float4*)&src[q * 8 + 4];
        union { u16x8 v; unsigned short s[8]; } o;
        o.s[0] = f2bf(a.x); o.s[1] = f2bf(a.y); o.s[2] = f2bf(a.z); o.s[3] = f2bf(a.w);
        o.s[4] = f2bf(b.x); o.s[5] = f2bf(b.y); o.s[6] = f2bf(b.z); o.s[7] = f2bf(b.w);
        *(u16x8*)&dst[q * 8] = o.v;
    }
}

// ---------------------------------------------------------------------------
// edge kernel (R13 dataflow) with REGISTER DIET -> 6 blocks/CU:
//  - Vp (random, long-latency) prefetched as 4x16B; Up (sorted, L1/L2-hot)
//    consumed AT USE in the epilogue (frees 16 unified regs at peak).
//  - unified VGPR+AGPR peak ~72-76 <= 85 = 512/6 cap (R12/R14 lesson:
//    launch bounds constrain the UNIFIED file; spill tripwire = WRITE_SIZE).
// ---------------------------------------------------------------------------
__global__ __launch_bounds__(256, 6) void edge_kernel(
    const unsigned short* __restrict__ Up,   // 50000 x 128 bf16, permuted rows
    const unsigned short* __restrict__ Vp,   // 50000 x 128 bf16, permuted rows
    const unsigned short* __restrict__ evs,  // E x 16 bf16, sorted
    const unsigned int* __restrict__ iuv_s,  // E packed (iu | iv<<16), sorted
    const unsigned short* __restrict__ Wef,  // layer-1 A frags (We^T, K=32 pad)
    const float* __restrict__ gb1,
    const unsigned short* __restrict__ W2f,  // layer-2 B frags
    const float* __restrict__ gb2,
    float* __restrict__ agg)
{
    __shared__ unsigned short sH1[64 * 136];  // aliased as sH2 f32 [64][68]
    __shared__ int sIu[64];

    const int tid = threadIdx.x;
    const int e0 = blockIdx.x * 64;
    const int wid = tid >> 6, lane = tid & 63;
    const int lo = lane & 15, hi = lane >> 4;
    const int g = e0 + wid * 16 + lo;         // this lane's (sorted) edge

    const unsigned iuv = iuv_s[g];
    const int iu = (int)(iuv & 0xFFFFu);
    const int iv = (int)(iuv >> 16);
    if (hi == 0) sIu[wid * 16 + lo] = iu;     // wave-local write

    // ---- register-prefetch ONLY the random Vp gather: 4 contiguous 16B ----
    u16x8 vpv[4];
#pragma unroll
    for (int ctp = 0; ctp < 4; ++ctp)
        vpv[ctp] = *(const u16x8*)&Vp[(size_t)iv * 128 + hi * 32 + ctp * 8];

    // ---- layer 1 MFMA: B-frag = evs row (coalesced); A = Wef (L1-hot) ----
    bf16x8 bfrag;
    if (hi < 2) {
        bfrag = *(const bf16x8*)&evs[(size_t)g * 16 + hi * 8];
    } else {
        bfrag = (bf16x8)(short)0;             // K-pad 16->32
    }

    f32x4 acc[8];
#pragma unroll
    for (int ct = 0; ct < 8; ++ct) {
#pragma unroll
        for (int r = 0; r < 4; ++r) acc[ct][r] = 0.f;
        bf16x8 a = *(const bf16x8*)&Wef[(size_t)((ct * 64 + lane) * 8)];
        acc[ct] = __builtin_amdgcn_mfma_f32_16x16x32_bf16(a, bfrag, acc[ct], 0, 0, 0);
    }

    // epilogue: h1 = relu(acc + b1 + Up[iu] + Vp[iv]) -> bf16 LDS (wave-local)
    // Up loaded AT USE (sorted -> cache-hot); vpv[ctp] holds cts {2ctp,2ctp+1}.
    const int e_loc = wid * 16 + lo;
#pragma unroll
    for (int ctp = 0; ctp < 4; ++ctp) {
        u16x8 uv = *(const u16x8*)&Up[(size_t)iu * 128 + hi * 32 + ctp * 8];
        u16x8 vv = vpv[ctp];
#pragma unroll
        for (int half = 0; half < 2; ++half) {
            const int ct = ctp * 2 + half;
            const int c0 = ct * 16 + hi * 4;
            float4 b1 = *(const float4*)&gb1[c0];
            ushort4 h;
            h.x = f2bf(relu(acc[ct][0] + b1.x + bf2f(uv[half * 4 + 0]) + bf2f(vv[half * 4 + 0])));
            h.y = f2bf(relu(acc[ct][1] + b1.y + bf2f(uv[half * 4 + 1]) + bf2f(vv[half * 4 + 1])));
            h.z = f2bf(relu(acc[ct][2] + b1.z + bf2f(uv[half * 4 + 2]) + bf2f(vv[half * 4 + 2])));
            h.w = f2bf(relu(acc[ct][3] + b1.w + bf2f(uv[half * 4 + 3]) + bf2f(vv[half * 4 + 3])));
            *(ushort4*)&sH1[e_loc * 136 + c0] = h;
        }
    }
    // intra-wave ushort write->read on same array: compiler-ordered, no barrier

    // ---- layer 2 via MFMA: wave reads its OWN 16 rows of sH1 ----
    f32x4 accm[4];
#pragma unroll
    for (int nt = 0; nt < 4; ++nt)
#pragma unroll
        for (int r = 0; r < 4; ++r) accm[nt][r] = 0.f;

#pragma unroll
    for (int ks = 0; ks < 4; ++ks) {
        bf16x8 a = *(const bf16x8*)&sH1[(wid * 16 + lo) * 136 + ks * 32 + hi * 8];
#pragma unroll
        for (int nt = 0; nt < 4; ++nt) {
            bf16x8 b = *(const bf16x8*)&W2f[(size_t)(((ks * 4 + nt) * 64 + lane) * 8)];
            accm[nt] = __builtin_amdgcn_mfma_f32_16x16x32_bf16(a, b, accm[nt], 0, 0, 0);
        }
    }
    __syncthreads();   // alias (ushort->float) boundary: all sH1 reads done

    float* sH2 = (float*)sH1;   // [64][68] fp32; wave-local byte range coincides
#pragma unroll
    for (int nt = 0; nt < 4; ++nt) {
        int col = nt * 16 + lo;
        float b2v = gb2[col];
        int erow = wid * 16 + hi * 4;
#pragma unroll
        for (int r = 0; r < 4; ++r)
            sH2[(erow + r) * 68 + col] = relu(accm[nt][r] + b2v);
    }
    // reduction reads own wave's rows (float->float, intra-wave): no barrier

    // ---- segmented reduction over sorted iu: thread = (col, own wave) ----
    {
        const int c = tid & 63;       // output column
        const int eq0 = wid * 16;     // this wave's 16 edges
        int   iu_cur = sIu[eq0];
        float running = 0.f;
#pragma unroll
        for (int k = 0; k < 16; ++k) {
            int e = eq0 + k;
            int iu2 = sIu[e];
            if (iu2 != iu_cur) {
                atomicAdd(&agg[(size_t)iu_cur * 64 + c], running);
                running = 0.f;
                iu_cur = iu2;
            }
            running += sH2[e * 68 + c];
        }
        atomicAdd(&agg[(size_t)iu_cur * 64 + c], running);
    }
}

// ---------------------------------------------------------------------------
// node kernel via MFMA: out = relu(relu([u,agg] @ fw1 + fb1) @ fw2 + fb2)
// ---------------------------------------------------------------------------
__global__ __launch_bounds__(256) void node_kernel(
    const float* __restrict__ u, const float* __restrict__ agg,
    const unsigned short* __restrict__ F1f, const float* __restrict__ fb1,
    const unsigned short* __restrict__ F2f, const float* __restrict__ fb2,
    float* __restrict__ out, int N)
{
    __shared__ unsigned short sY[64 * 136];   // y bf16, wave-local rows
    const int tid = threadIdx.x;
    const int wid = tid >> 6, lane = tid & 63;
    const int lo = lane & 15, hi = lane >> 4;
    const int row0 = blockIdx.x * 64;
    const int row = row0 + wid * 16 + lo;
    const int rl = (row < N) ? row : (N - 1);

    bf16x8 a0, a1, a2, a3;
    {
        union { bf16x8 v; unsigned short s[8]; } r0_, r1_, r2_, r3_;
        float4 x0 = *(const float4*)&u[(size_t)rl * 64 + hi * 8];
        float4 x1 = *(const float4*)&u[(size_t)rl * 64 + hi * 8 + 4];
        float4 x2 = *(const float4*)&u[(size_t)rl * 64 + 32 + hi * 8];
        float4 x3 = *(const float4*)&u[(size_t)rl * 64 + 32 + hi * 8 + 4];
        float4 g0 = *(const float4*)&agg[(size_t)rl * 64 + hi * 8];
        float4 g1 = *(const float4*)&agg[(size_t)rl * 64 + hi * 8 + 4];
        float4 g2 = *(const float4*)&agg[(size_t)rl * 64 + 32 + hi * 8];
        float4 g3 = *(const float4*)&agg[(size_t)rl * 64 + 32 + hi * 8 + 4];
        r0_.s[0] = f2bf(x0.x); r0_.s[1] = f2bf(x0.y); r0_.s[2] = f2bf(x0.z); r0_.s[3] = f2bf(x0.w);
        r0_.s[4] = f2bf(x1.x); r0_.s[5] = f2bf(x1.y); r0_.s[6] = f2bf(x1.z); r0_.s[7] = f2bf(x1.w);
        r1_.s[0] = f2bf(x2.x); r1_.s[1] = f2bf(x2.y); r1_.s[2] = f2bf(x2.z); r1_.s[3] = f2bf(x2.w);
        r1_.s[4] = f2bf(x3.x); r1_.s[5] = f2bf(x3.y); r1_.s[6] = f2bf(x3.z); r1_.s[7] = f2bf(x3.w);
        r2_.s[0] = f2bf(g0.x); r2_.s[1] = f2bf(g0.y); r2_.s[2] = f2bf(g0.z); r2_.s[3] = f2bf(g0.w);
        r2_.s[4] = f2bf(g1.x); r2_.s[5] = f2bf(g1.y); r2_.s[6] = f2bf(g1.z); r2_.s[7] = f2bf(g1.w);
        r3_.s[0] = f2bf(g2.x); r3_.s[1] = f2bf(g2.y); r3_.s[2] = f2bf(g2.z); r3_.s[3] = f2bf(g2.w);
        r3_.s[4] = f2bf(g3.x); r3_.s[5] = f2bf(g3.y); r3_.s[6] = f2bf(g3.z); r3_.s[7] = f2bf(g3.w);
        a0 = r0_.v; a1 = r1_.v; a2 = r2_.v; a3 = r3_.v;
    }

    // ---- layer 1: y = relu(x @ fw1 + fb1), 32 MFMAs/wave ----
#pragma unroll
    for (int nt = 0; nt < 8; ++nt) {
        f32x4 acc;
#pragma unroll
        for (int r = 0; r < 4; ++r) acc[r] = 0.f;
        bf16x8 b0 = *(const bf16x8*)&F1f[(size_t)(((0 * 8 + nt) * 64 + lane) * 8)];
        bf16x8 b1 = *(const bf16x8*)&F1f[(size_t)(((1 * 8 + nt) * 64 + lane) * 8)];
        bf16x8 b2 = *(const bf16x8*)&F1f[(size_t)(((2 * 8 + nt) * 64 + lane) * 8)];
        bf16x8 b3 = *(const bf16x8*)&F1f[(size_t)(((3 * 8 + nt) * 64 + lane) * 8)];
        acc = __builtin_amdgcn_mfma_f32_16x16x32_bf16(a0, b0, acc, 0, 0, 0);
        acc = __builtin_amdgcn_mfma_f32_16x16x32_bf16(a1, b1, acc, 0, 0, 0);
        acc = __builtin_amdgcn_mfma_f32_16x16x32_bf16(a2, b2, acc, 0, 0, 0);
        acc = __builtin_amdgcn_mfma_f32_16x16x32_bf16(a3, b3, acc, 0, 0, 0);
        int col = nt * 16 + lo;
        float b1v = fb1[col];
        int rbase = wid * 16 + hi * 4;
#pragma unroll
        for (int r = 0; r < 4; ++r)
            sY[(rbase + r) * 136 + col] = f2bf(relu(acc[r] + b1v));
    }

    // ---- layer 2: out = relu(y @ fw2 + fb2), 16 MFMAs/wave ----
    bf16x8 ya0 = *(const bf16x8*)&sY[(wid * 16 + lo) * 136 + 0 * 32 + hi * 8];
    bf16x8 ya1 = *(const bf16x8*)&sY[(wid * 16 + lo) * 136 + 1 * 32 + hi * 8];
    bf16x8 ya2 = *(const bf16x8*)&sY[(wid * 16 + lo) * 136 + 2 * 32 + hi * 8];
    bf16x8 ya3 = *(const bf16x8*)&sY[(wid * 16 + lo) * 136 + 3 * 32 + hi * 8];
#pragma unroll
    for (int nt = 0; nt < 4; ++nt) {
        f32x4 acc;
#pragma unroll
        for (int r = 0; r < 4; ++r) acc[r] = 0.f;
        bf16x8 b0 = *(const bf16x8*)&F2f[(size_t)(((0 * 4 + nt) * 64 + lane) * 8)];
        bf16x8 b1 = *(const bf16x8*)&F2f[(size_t)(((1 * 4 + nt) * 64 + lane) * 8)];
        bf16x8 b2 = *(const bf16x8*)&F2f[(size_t)(((2 * 4 + nt) * 64 + lane) * 8)];
        bf16x8 b3 = *(const bf16x8*)&F2f[(size_t)(((3 * 4 + nt) * 64 + lane) * 8)];
        acc = __builtin_amdgcn_mfma_f32_16x16x32_bf16(ya0, b0, acc, 0, 0, 0);
        acc = __builtin_amdgcn_mfma_f32_16x16x32_bf16(ya1, b1, acc, 0, 0, 0);
        acc = __builtin_amdgcn_mfma_f32_16x16x32_bf16(ya2, b2, acc, 0, 0, 0);
        acc = __builtin_amdgcn_mfma_f32_16x16x32_bf16(ya3, b3, acc, 0, 0, 0);
        int col = nt * 16 + lo;
        float b2v = fb2[col];
#pragma unroll
        for (int r = 0; r < 4; ++r) {
            int gr = row0 + wid * 16 + hi * 4 + r;
            if (gr < N) out[(size_t)gr * 64 + col] = relu(acc[r] + b2v);
        }
    }
}

// ---------------------------------------------------------------------------
extern "C" void kernel_launch(void* const* d_in, const int* in_sizes, int n_in,
                              void* d_out, int out_size, void* d_ws, size_t ws_size,
                              hipStream_t stream)
{
    const float* u   = (const float*)d_in[0];
    const float* v   = (const float*)d_in[1];
    const float* ev  = (const float*)d_in[2];
    const int*   eiv = (const int*)d_in[3];
    const int*   eiu = (const int*)d_in[4];
    const float* gw1 = (const float*)d_in[5];   // 144 x 128
    const float* gb1 = (const float*)d_in[6];   // 128
    const float* gw2 = (const float*)d_in[7];   // 128 x 64
    const float* gb2 = (const float*)d_in[8];   // 64
    const float* fw1 = (const float*)d_in[9];   // 128 x 128
    const float* fb1 = (const float*)d_in[10];  // 128
    const float* fw2 = (const float*)d_in[11];  // 128 x 64
    const float* fb2 = (const float*)d_in[12];  // 64
    float* out = (float*)d_out;

    // workspace layout (agg and counts adjacent -> single memset); ~67.5 MB
    unsigned short* Up     = (unsigned short*)d_ws;                 // 50000x128 bf16
    unsigned short* Vp     = Up + (size_t)U_N * 128;                // 50000x128 bf16
    unsigned short* evs    = Vp + (size_t)V_N * 128;                // E x 16 bf16
    float*          agg    = (float*)(evs + (size_t)E_N * 16);      // 50000x64 f32
    int*            counts = (int*)(agg + (size_t)U_N * 64);        // NBINS (= cursor)
    unsigned int*   iuv_s  = (unsigned int*)(counts + NBINS);       // 800000
    unsigned short* W2f    = (unsigned short*)(iuv_s + E_N);        // 8192 bf16
    unsigned short* Wef    = W2f + 8192;                            // 4096 bf16
    unsigned short* F1f    = Wef + 4096;                            // 16384 bf16
    unsigned short* F2f    = F1f + 16384;                           // 8192 bf16
    int*            bsum   = (int*)(F2f + 8192);                    // NSCAN ints

    // one memset covers agg (zero init) + counts (hist init)
    hipMemsetAsync(agg, 0, ((size_t)U_N * 64 + NBINS) * sizeof(float), stream);

    dim3 blk(256);
    prep_kernel<<<dim3(2 * NB_PROJ + 1 + NB_HIST), blk, 0, stream>>>(
        eiu, counts, u, v, gw1, gw2, fw1, fw2, Up, Vp, W2f, Wef, F1f, F2f);
    scan_sums<<<dim3(NSCAN), blk, 0, stream>>>(counts, bsum);
    scan_bsum<<<dim3(1), dim3(512), 0, stream>>>(bsum);
    scan_apply<<<dim3(NSCAN), blk, 0, stream>>>(counts, bsum);
    permute_kernel<<<dim3(NB_HIST), blk, 0, stream>>>(
        eiu, eiv, ev, counts, iuv_s, evs);

    edge_kernel<<<dim3(E_N / 64), blk, 0, stream>>>(
        Up, Vp, evs, iuv_s, Wef, gb1, W2f, gb2, agg);
    node_kernel<<<dim3((U_N + 63) / 64), blk, 0, stream>>>(
        u, agg, F1f, fb1, F2f, fb2, out, U_N);
}

// Round 16
// 200.518 us; speedup vs baseline: 1.2859x; 1.1426x over previous
//
#include <hip/hip_runtime.h>

// Problem constants (match reference)
constexpr int U_N = 50000;
constexpr int V_N = 50000;
constexpr int E_N = 800000;   // == 64 * 12500
// dims: F=64, G=64, H=16; g: 144->128->64; f: 128->128->64

typedef float f32x4 __attribute__((ext_vector_type(4)));
typedef short bf16x8 __attribute__((ext_vector_type(8)));
typedef unsigned short u16x8 __attribute__((ext_vector_type(8)));

__device__ __forceinline__ float relu(float x) { return fmaxf(x, 0.f); }

// round-to-nearest-even fp32 -> bf16 bits
__device__ __forceinline__ unsigned short f2bf(float f) {
    unsigned u = __float_as_uint(f);
    unsigned rounding = 0x7FFFu + ((u >> 16) & 1u);
    return (unsigned short)((u + rounding) >> 16);
}
__device__ __forceinline__ float bf2f(unsigned short b) {
    return __uint_as_float(((unsigned)b) << 16);
}

constexpr int NB_HIST = (E_N + 255) / 256;   // 3125
constexpr int NB_PROJ = (U_N + 63) / 64;     // 782
constexpr int NBINS = U_N;                   // 50000
constexpr int NSCAN = (NBINS + 1023) / 1024; // 49

// Up/Vp rows are stored FRAGMENT-PERMUTED: element (col = ct*16 + hi*4 + j)
// lives at row offset hi*32 + ct*4 + j  (hi 0..3, ct 0..7, j 0..3).
// => each edge-kernel lane's 64B of gather data is CONTIGUOUS: 4 x 16B loads.

// ---------------------------------------------------------------------------
// proj via MFMA: P[row][*] = bf16(X[.][64]) @ bf16(W[64][128]), permuted store
// ---------------------------------------------------------------------------
__device__ __forceinline__ void proj_mfma(const float* __restrict__ X,
                                          const float* __restrict__ W,  // 64x128
                                          unsigned short* __restrict__ P,
                                          int N, int row0,
                                          unsigned short* sWf)
{
    const int tid = threadIdx.x;

    for (int idx = tid; idx < 64 * 128 / 4; idx += 256) {
        int k  = (idx * 4) >> 7;
        int n0 = (idx * 4) & 127;
        float4 w = *(const float4*)&W[k * 128 + n0];
        int ks = k >> 5, hi = (k & 31) >> 3, j = k & 7;
        float wv[4] = {w.x, w.y, w.z, w.w};
#pragma unroll
        for (int q = 0; q < 4; ++q) {
            int n = n0 + q, nt = n >> 4, lo = n & 15;
            sWf[((ks * 8 + nt) * 64 + hi * 16 + lo) * 8 + j] = f2bf(wv[q]);
        }
    }
    __syncthreads();

    const int wid = tid >> 6, lane = tid & 63;
    const int lo = lane & 15, hi = lane >> 4;
    const int row = row0 + wid * 16 + lo;
    const int rl = (row < N) ? row : (N - 1);

    bf16x8 a0, a1;
    {
        union { bf16x8 v; unsigned short s[8]; } ra, rb;
        float4 x0 = *(const float4*)&X[(size_t)rl * 64 + hi * 8];
        float4 x1 = *(const float4*)&X[(size_t)rl * 64 + hi * 8 + 4];
        ra.s[0] = f2bf(x0.x); ra.s[1] = f2bf(x0.y); ra.s[2] = f2bf(x0.z); ra.s[3] = f2bf(x0.w);
        ra.s[4] = f2bf(x1.x); ra.s[5] = f2bf(x1.y); ra.s[6] = f2bf(x1.z); ra.s[7] = f2bf(x1.w);
        float4 y0 = *(const float4*)&X[(size_t)rl * 64 + 32 + hi * 8];
        float4 y1 = *(const float4*)&X[(size_t)rl * 64 + 32 + hi * 8 + 4];
        rb.s[0] = f2bf(y0.x); rb.s[1] = f2bf(y0.y); rb.s[2] = f2bf(y0.z); rb.s[3] = f2bf(y0.w);
        rb.s[4] = f2bf(y1.x); rb.s[5] = f2bf(y1.y); rb.s[6] = f2bf(y1.z); rb.s[7] = f2bf(y1.w);
        a0 = ra.v; a1 = rb.v;
    }

    const int rbase = row0 + wid * 16 + hi * 4;
    const int ph = lo >> 2, pj = lo & 3;   // permuted-store decomposition of col
#pragma unroll
    for (int nt = 0; nt < 8; ++nt) {
        f32x4 acc;
#pragma unroll
        for (int r = 0; r < 4; ++r) acc[r] = 0.f;
        bf16x8 b0 = *(const bf16x8*)&sWf[((0 * 8 + nt) * 64 + lane) * 8];
        bf16x8 b1 = *(const bf16x8*)&sWf[((1 * 8 + nt) * 64 + lane) * 8];
        acc = __builtin_amdgcn_mfma_f32_16x16x32_bf16(a0, b0, acc, 0, 0, 0);
        acc = __builtin_amdgcn_mfma_f32_16x16x32_bf16(a1, b1, acc, 0, 0, 0);
#pragma unroll
        for (int r = 0; r < 4; ++r) {
            int gr = rbase + r;
            // col = nt*16 + lo  ->  permuted pos = (lo>>2)*32 + nt*4 + (lo&3)
            if (gr < N) P[(size_t)gr * 128 + ph * 32 + nt * 4 + pj] = f2bf(acc[r]);
        }
    }
}

// ---------------------------------------------------------------------------
// prep kernel: projU (MFMA), projV (MFMA), weight-pack, histogram.
// ---------------------------------------------------------------------------
__global__ __launch_bounds__(256) void prep_kernel(
    const int* __restrict__ idx_u, int* __restrict__ counts,
    const float* __restrict__ u, const float* __restrict__ v,
    const float* __restrict__ gw1, const float* __restrict__ gw2,
    const float* __restrict__ fw1, const float* __restrict__ fw2,
    unsigned short* __restrict__ Up, unsigned short* __restrict__ Vp,
    unsigned short* __restrict__ W2f, unsigned short* __restrict__ Wef,
    unsigned short* __restrict__ F1f, unsigned short* __restrict__ F2f)
{
    __shared__ unsigned short sWf[8192];   // proj branches only
    int b = blockIdx.x;

    if (b < NB_PROJ) {
        proj_mfma(u, gw1, Up, U_N, b * 64, sWf);
        return;
    }
    b -= NB_PROJ;
    if (b < NB_PROJ) {
        proj_mfma(v, gw1 + 64 * 128, Vp, V_N, b * 64, sWf);
        return;
    }
    b -= NB_PROJ;
    if (b == 0) {
        const int tid = threadIdx.x;
        // W2f (edge L2, gw2 128x64) and F2f (node L2, fw2 128x64): same layout
        for (int t = tid; t < 4 * 4 * 64 * 8; t += 256) {
            int j    = t & 7;
            int lane = (t >> 3) & 63;
            int nt   = (t >> 9) & 3;
            int ks   = t >> 11;
            int n = nt * 16 + (lane & 15);
            int k = ks * 32 + (lane >> 4) * 8 + j;
            W2f[t] = f2bf(gw2[k * 64 + n]);
            F2f[t] = f2bf(fw2[k * 64 + n]);
        }
        // Wef (edge L1 A-frags, We^T, K padded to 32)
        const float* gw1e = gw1 + 128 * 128;   // 16 x 128
        for (int t = tid; t < 8 * 64 * 8; t += 256) {
            int j    = t & 7;
            int lane = (t >> 3) & 63;
            int ct   = t >> 9;
            int c = ct * 16 + (lane & 15);
            int k = (lane >> 4) * 8 + j;
            Wef[t] = (k < 16) ? f2bf(gw1e[k * 128 + c]) : (unsigned short)0;
        }
        // F1f (node L1, fw1 128x128): ks 0..3, nt 0..7
        for (int t = tid; t < 4 * 8 * 64 * 8; t += 256) {
            int j    = t & 7;
            int lane = (t >> 3) & 63;
            int nt   = (t >> 9) & 7;
            int ks   = t >> 12;
            int n = nt * 16 + (lane & 15);
            int k = ks * 32 + (lane >> 4) * 8 + j;
            F1f[t] = f2bf(fw1[k * 128 + n]);
        }
        return;
    }
    b -= 1;
    // ---- histogram (key = iu) ----
    int e = b * 256 + threadIdx.x;
    if (e < E_N) atomicAdd(&counts[idx_u[e]], 1);
}

// ---------------------------------------------------------------------------
// multi-block exclusive scan of counts[0..NBINS): sums -> scan sums -> apply
// ---------------------------------------------------------------------------
__global__ __launch_bounds__(256) void scan_sums(const int* __restrict__ counts,
                                                 int* __restrict__ bsum)
{
    __shared__ int sred[256];
    const int tid = threadIdx.x;
    int base = blockIdx.x * 1024 + tid * 4;
    int s = 0;
    if (base + 3 < NBINS) {
        int4 c = *(const int4*)&counts[base];
        s = c.x + c.y + c.z + c.w;
    } else {
#pragma unroll
        for (int k = 0; k < 4; ++k) { int i = base + k; if (i < NBINS) s += counts[i]; }
    }
    sred[tid] = s;
    __syncthreads();
    for (int off = 128; off > 0; off >>= 1) {
        if (tid < off) sred[tid] += sred[tid + off];
        __syncthreads();
    }
    if (tid == 0) bsum[blockIdx.x] = sred[0];
}

__global__ __launch_bounds__(512) void scan_bsum(int* __restrict__ bsum)
{
    __shared__ int sScan[512];
    const int tid = threadIdx.x;
    int vIn = (tid < NSCAN) ? bsum[tid] : 0;
    sScan[tid] = vIn;
    __syncthreads();
    for (int off = 1; off < 512; off <<= 1) {
        int val = (tid >= off) ? sScan[tid - off] : 0;
        __syncthreads();
        sScan[tid] += val;
        __syncthreads();
    }
    if (tid < NSCAN) bsum[tid] = sScan[tid] - vIn;   // exclusive
}

__global__ __launch_bounds__(256) void scan_apply(int* __restrict__ counts,
                                                  const int* __restrict__ bsum)
{
    __shared__ int sScan[256];
    const int tid = threadIdx.x;
    int base = blockIdx.x * 1024 + tid * 4;
    int v0 = 0, v1 = 0, v2 = 0, v3 = 0;
    if (base + 3 < NBINS) {
        int4 c = *(const int4*)&counts[base];
        v0 = c.x; v1 = c.y; v2 = c.z; v3 = c.w;
    } else {
        if (base     < NBINS) v0 = counts[base];
        if (base + 1 < NBINS) v1 = counts[base + 1];
        if (base + 2 < NBINS) v2 = counts[base + 2];
        if (base + 3 < NBINS) v3 = counts[base + 3];
    }
    int tsum = v0 + v1 + v2 + v3;
    sScan[tid] = tsum;
    __syncthreads();
    for (int off = 1; off < 256; off <<= 1) {
        int val = (tid >= off) ? sScan[tid - off] : 0;
        __syncthreads();
        sScan[tid] += val;
        __syncthreads();
    }
    int excl = sScan[tid] - tsum + bsum[blockIdx.x];
    if (base     < NBINS) counts[base]     = excl;
    if (base + 1 < NBINS) counts[base + 1] = excl + v0;
    if (base + 2 < NBINS) counts[base + 2] = excl + v0 + v1;
    if (base + 3 < NBINS) counts[base + 3] = excl + v0 + v1 + v2;
}

// ---------------------------------------------------------------------------
// permute+gather: scatter edges into iu-sorted order, pre-gathering
// iuv packed indices + ev row as bf16 (two 16B stores per edge).
// ---------------------------------------------------------------------------
__global__ __launch_bounds__(256) void permute_kernel(
    const int* __restrict__ idx_u, const int* __restrict__ idx_v,
    const float* __restrict__ ev, int* __restrict__ cursor,
    unsigned int* __restrict__ iuv_s, unsigned short* __restrict__ evs)
{
    int e = blockIdx.x * 256 + threadIdx.x;
    if (e >= E_N) return;
    int iu = idx_u[e];
    int iv = idx_v[e];
    int pos = atomicAdd(&cursor[iu], 1);
    iuv_s[pos] = (unsigned)iu | ((unsigned)iv << 16);

    const float* src = &ev[(size_t)e * 16];
    unsigned short* dst = &evs[(size_t)pos * 16];
#pragma unroll
    for (int q = 0; q < 2; ++q) {
        float4 a = *(const float4*)&src[q * 8];
        float4 b = *(const float4*)&src[q * 8 + 4];
        union { u16x8 v; unsigned short s[8]; } o;
        o.s[0] = f2bf(a.x); o.s[1] = f2bf(a.y); o.s[2] = f2bf(a.z); o.s[3] = f2bf(a.w);
        o.s[4] = f2bf(b.x); o.s[5] = f2bf(b.y); o.s[6] = f2bf(b.z); o.s[7] = f2bf(b.w);
        *(u16x8*)&dst[q * 8] = o.v;
    }
}

// ---------------------------------------------------------------------------
// edge kernel (R15 dataflow) with W2f/gb1/gb2 staged in LDS:
//   per-wave global-load count drops ~42 -> ~18 (weight re-reads move to the
//   LDS pipe, off the contended TA/L1 path). LDS 34.6 KB -> 4 blocks/CU.
//   Wef stays global (8 loads, hidden under Vp gather latency; keeps LDS
//   under the 40 KB 4-block boundary). Spill tripwire: WRITE_SIZE.
// ---------------------------------------------------------------------------
__global__ __launch_bounds__(256, 4) void edge_kernel(
    const unsigned short* __restrict__ Up,   // 50000 x 128 bf16, permuted rows
    const unsigned short* __restrict__ Vp,   // 50000 x 128 bf16, permuted rows
    const unsigned short* __restrict__ evs,  // E x 16 bf16, sorted
    const unsigned int* __restrict__ iuv_s,  // E packed (iu | iv<<16), sorted
    const unsigned short* __restrict__ Wef,  // layer-1 A frags (We^T, K=32 pad)
    const float* __restrict__ gb1,
    const unsigned short* __restrict__ W2f,  // layer-2 B frags
    const float* __restrict__ gb2,
    float* __restrict__ agg)
{
    __shared__ unsigned short sH1[64 * 136];  // 17408 B; aliased as sH2 f32 [64][68]
    __shared__ unsigned short sW2f[8192];     // 16 KB
    __shared__ float sB1[128];                // 512 B
    __shared__ float sB2[64];                 // 256 B
    __shared__ int sIu[64];

    const int tid = threadIdx.x;
    const int e0 = blockIdx.x * 64;
    const int wid = tid >> 6, lane = tid & 63;
    const int lo = lane & 15, hi = lane >> 4;
    const int g = e0 + wid * 16 + lo;         // this lane's (sorted) edge

    const unsigned iuv = iuv_s[g];
    const int iu = (int)(iuv & 0xFFFFu);
    const int iv = (int)(iuv >> 16);
    if (hi == 0) sIu[wid * 16 + lo] = iu;

    // ---- register-prefetch ONLY the random Vp gather: 4 contiguous 16B ----
    u16x8 vpv[4];
#pragma unroll
    for (int ctp = 0; ctp < 4; ++ctp)
        vpv[ctp] = *(const u16x8*)&Vp[(size_t)iv * 128 + hi * 32 + ctp * 8];

    // ---- stage shared weights into LDS (overlaps gather latency) ----
#pragma unroll
    for (int i = 0; i < 4; ++i)
        *(u16x8*)&sW2f[tid * 8 + i * 2048] = *(const u16x8*)&W2f[tid * 8 + i * 2048];
    if (tid < 32) *(float4*)&sB1[tid * 4] = *(const float4*)&gb1[tid * 4];
    else if (tid < 48) *(float4*)&sB2[(tid - 32) * 4] = *(const float4*)&gb2[(tid - 32) * 4];

    // ---- layer 1 MFMA: B-frag = evs row (coalesced); A = Wef (global) ----
    bf16x8 bfrag;
    if (hi < 2) {
        bfrag = *(const bf16x8*)&evs[(size_t)g * 16 + hi * 8];
    } else {
        bfrag = (bf16x8)(short)0;             // K-pad 16->32
    }

    f32x4 acc[8];
#pragma unroll
    for (int ct = 0; ct < 8; ++ct) {
#pragma unroll
        for (int r = 0; r < 4; ++r) acc[ct][r] = 0.f;
        bf16x8 a = *(const bf16x8*)&Wef[(size_t)((ct * 64 + lane) * 8)];
        acc[ct] = __builtin_amdgcn_mfma_f32_16x16x32_bf16(a, bfrag, acc[ct], 0, 0, 0);
    }

    __syncthreads();   // staging (sW2f/sB1/sB2) + sIu visible to all waves

    // epilogue: h1 = relu(acc + b1 + Up[iu] + Vp[iv]) -> bf16 LDS (wave-local)
    // Up loaded AT USE (sorted -> cache-hot); vpv[ctp] holds cts {2ctp,2ctp+1}.
    const int e_loc = wid * 16 + lo;
#pragma unroll
    for (int ctp = 0; ctp < 4; ++ctp) {
        u16x8 uv = *(const u16x8*)&Up[(size_t)iu * 128 + hi * 32 + ctp * 8];
        u16x8 vv = vpv[ctp];
#pragma unroll
        for (int half = 0; half < 2; ++half) {
            const int ct = ctp * 2 + half;
            const int c0 = ct * 16 + hi * 4;
            float4 b1 = *(const float4*)&sB1[c0];
            ushort4 h;
            h.x = f2bf(relu(acc[ct][0] + b1.x + bf2f(uv[half * 4 + 0]) + bf2f(vv[half * 4 + 0])));
            h.y = f2bf(relu(acc[ct][1] + b1.y + bf2f(uv[half * 4 + 1]) + bf2f(vv[half * 4 + 1])));
            h.z = f2bf(relu(acc[ct][2] + b1.z + bf2f(uv[half * 4 + 2]) + bf2f(vv[half * 4 + 2])));
            h.w = f2bf(relu(acc[ct][3] + b1.w + bf2f(uv[half * 4 + 3]) + bf2f(vv[half * 4 + 3])));
            *(ushort4*)&sH1[e_loc * 136 + c0] = h;
        }
    }
    // intra-wave ushort write->read on same array: compiler-ordered, no barrier

    // ---- layer 2 via MFMA: wave reads its OWN 16 rows of sH1; W2f from LDS ----
    f32x4 accm[4];
#pragma unroll
    for (int nt = 0; nt < 4; ++nt)
#pragma unroll
        for (int r = 0; r < 4; ++r) accm[nt][r] = 0.f;

#pragma unroll
    for (int ks = 0; ks < 4; ++ks) {
        bf16x8 a = *(const bf16x8*)&sH1[(wid * 16 + lo) * 136 + ks * 32 + hi * 8];
#pragma unroll
        for (int nt = 0; nt < 4; ++nt) {
            bf16x8 b = *(const bf16x8*)&sW2f[((ks * 4 + nt) * 64 + lane) * 8];
            accm[nt] = __builtin_amdgcn_mfma_f32_16x16x32_bf16(a, b, accm[nt], 0, 0, 0);
        }
    }
    __syncthreads();   // alias (ushort->float) boundary: all sH1 reads done

    float* sH2 = (float*)sH1;   // [64][68] fp32; wave-local byte range coincides
#pragma unroll
    for (int nt = 0; nt < 4; ++nt) {
        int col = nt * 16 + lo;
        float b2v = sB2[col];
        int erow = wid * 16 + hi * 4;
#pragma unroll
        for (int r = 0; r < 4; ++r)
            sH2[(erow + r) * 68 + col] = relu(accm[nt][r] + b2v);
    }
    // reduction reads own wave's rows (float->float, intra-wave): no barrier

    // ---- segmented reduction over sorted iu: thread = (col, own wave) ----
    {
        const int c = tid & 63;       // output column
        const int eq0 = wid * 16;     // this wave's 16 edges
        int   iu_cur = sIu[eq0];
        float running = 0.f;
#pragma unroll
        for (int k = 0; k < 16; ++k) {
            int e = eq0 + k;
            int iu2 = sIu[e];
            if (iu2 != iu_cur) {
                atomicAdd(&agg[(size_t)iu_cur * 64 + c], running);
                running = 0.f;
                iu_cur = iu2;
            }
            running += sH2[e * 68 + c];
        }
        atomicAdd(&agg[(size_t)iu_cur * 64 + c], running);
    }
}

// ---------------------------------------------------------------------------
// node kernel via MFMA: out = relu(relu([u,agg] @ fw1 + fb1) @ fw2 + fb2)
// ---------------------------------------------------------------------------
__global__ __launch_bounds__(256) void node_kernel(
    const float* __restrict__ u, const float* __restrict__ agg,
    const unsigned short* __restrict__ F1f, const float* __restrict__ fb1,
    const unsigned short* __restrict__ F2f, const float* __restrict__ fb2,
    float* __restrict__ out, int N)
{
    __shared__ unsigned short sY[64 * 136];   // y bf16, wave-local rows
    const int tid = threadIdx.x;
    const int wid = tid >> 6, lane = tid & 63;
    const int lo = lane & 15, hi = lane >> 4;
    const int row0 = blockIdx.x * 64;
    const int row = row0 + wid * 16 + lo;
    const int rl = (row < N) ? row : (N - 1);

    bf16x8 a0, a1, a2, a3;
    {
        union { bf16x8 v; unsigned short s[8]; } r0_, r1_, r2_, r3_;
        float4 x0 = *(const float4*)&u[(size_t)rl * 64 + hi * 8];
        float4 x1 = *(const float4*)&u[(size_t)rl * 64 + hi * 8 + 4];
        float4 x2 = *(const float4*)&u[(size_t)rl * 64 + 32 + hi * 8];
        float4 x3 = *(const float4*)&u[(size_t)rl * 64 + 32 + hi * 8 + 4];
        float4 g0 = *(const float4*)&agg[(size_t)rl * 64 + hi * 8];
        float4 g1 = *(const float4*)&agg[(size_t)rl * 64 + hi * 8 + 4];
        float4 g2 = *(const float4*)&agg[(size_t)rl * 64 + 32 + hi * 8];
        float4 g3 = *(const float4*)&agg[(size_t)rl * 64 + 32 + hi * 8 + 4];
        r0_.s[0] = f2bf(x0.x); r0_.s[1] = f2bf(x0.y); r0_.s[2] = f2bf(x0.z); r0_.s[3] = f2bf(x0.w);
        r0_.s[4] = f2bf(x1.x); r0_.s[5] = f2bf(x1.y); r0_.s[6] = f2bf(x1.z); r0_.s[7] = f2bf(x1.w);
        r1_.s[0] = f2bf(x2.x); r1_.s[1] = f2bf(x2.y); r1_.s[2] = f2bf(x2.z); r1_.s[3] = f2bf(x2.w);
        r1_.s[4] = f2bf(x3.x); r1_.s[5] = f2bf(x3.y); r1_.s[6] = f2bf(x3.z); r1_.s[7] = f2bf(x3.w);
        r2_.s[0] = f2bf(g0.x); r2_.s[1] = f2bf(g0.y); r2_.s[2] = f2bf(g0.z); r2_.s[3] = f2bf(g0.w);
        r2_.s[4] = f2bf(g1.x); r2_.s[5] = f2bf(g1.y); r2_.s[6] = f2bf(g1.z); r2_.s[7] = f2bf(g1.w);
        r3_.s[0] = f2bf(g2.x); r3_.s[1] = f2bf(g2.y); r3_.s[2] = f2bf(g2.z); r3_.s[3] = f2bf(g2.w);
        r3_.s[4] = f2bf(g3.x); r3_.s[5] = f2bf(g3.y); r3_.s[6] = f2bf(g3.z); r3_.s[7] = f2bf(g3.w);
        a0 = r0_.v; a1 = r1_.v; a2 = r2_.v; a3 = r3_.v;
    }

    // ---- layer 1: y = relu(x @ fw1 + fb1), 32 MFMAs/wave ----
#pragma unroll
    for (int nt = 0; nt < 8; ++nt) {
        f32x4 acc;
#pragma unroll
        for (int r = 0; r < 4; ++r) acc[r] = 0.f;
        bf16x8 b0 = *(const bf16x8*)&F1f[(size_t)(((0 * 8 + nt) * 64 + lane) * 8)];
        bf16x8 b1 = *(const bf16x8*)&F1f[(size_t)(((1 * 8 + nt) * 64 + lane) * 8)];
        bf16x8 b2 = *(const bf16x8*)&F1f[(size_t)(((2 * 8 + nt) * 64 + lane) * 8)];
        bf16x8 b3 = *(const bf16x8*)&F1f[(size_t)(((3 * 8 + nt) * 64 + lane) * 8)];
        acc = __builtin_amdgcn_mfma_f32_16x16x32_bf16(a0, b0, acc, 0, 0, 0);
        acc = __builtin_amdgcn_mfma_f32_16x16x32_bf16(a1, b1, acc, 0, 0, 0);
        acc = __builtin_amdgcn_mfma_f32_16x16x32_bf16(a2, b2, acc, 0, 0, 0);
        acc = __builtin_amdgcn_mfma_f32_16x16x32_bf16(a3, b3, acc, 0, 0, 0);
        int col = nt * 16 + lo;
        float b1v = fb1[col];
        int rbase = wid * 16 + hi * 4;
#pragma unroll
        for (int r = 0; r < 4; ++r)
            sY[(rbase + r) * 136 + col] = f2bf(relu(acc[r] + b1v));
    }

    // ---- layer 2: out = relu(y @ fw2 + fb2), 16 MFMAs/wave ----
    bf16x8 ya0 = *(const bf16x8*)&sY[(wid * 16 + lo) * 136 + 0 * 32 + hi * 8];
    bf16x8 ya1 = *(const bf16x8*)&sY[(wid * 16 + lo) * 136 + 1 * 32 + hi * 8];
    bf16x8 ya2 = *(const bf16x8*)&sY[(wid * 16 + lo) * 136 + 2 * 32 + hi * 8];
    bf16x8 ya3 = *(const bf16x8*)&sY[(wid * 16 + lo) * 136 + 3 * 32 + hi * 8];
#pragma unroll
    for (int nt = 0; nt < 4; ++nt) {
        f32x4 acc;
#pragma unroll
        for (int r = 0; r < 4; ++r) acc[r] = 0.f;
        bf16x8 b0 = *(const bf16x8*)&F2f[(size_t)(((0 * 4 + nt) * 64 + lane) * 8)];
        bf16x8 b1 = *(const bf16x8*)&F2f[(size_t)(((1 * 4 + nt) * 64 + lane) * 8)];
        bf16x8 b2 = *(const bf16x8*)&F2f[(size_t)(((2 * 4 + nt) * 64 + lane) * 8)];
        bf16x8 b3 = *(const bf16x8*)&F2f[(size_t)(((3 * 4 + nt) * 64 + lane) * 8)];
        acc = __builtin_amdgcn_mfma_f32_16x16x32_bf16(ya0, b0, acc, 0, 0, 0);
        acc = __builtin_amdgcn_mfma_f32_16x16x32_bf16(ya1, b1, acc, 0, 0, 0);
        acc = __builtin_amdgcn_mfma_f32_16x16x32_bf16(ya2, b2, acc, 0, 0, 0);
        acc = __builtin_amdgcn_mfma_f32_16x16x32_bf16(ya3, b3, acc, 0, 0, 0);
        int col = nt * 16 + lo;
        float b2v = fb2[col];
#pragma unroll
        for (int r = 0; r < 4; ++r) {
            int gr = row0 + wid * 16 + hi * 4 + r;
            if (gr < N) out[(size_t)gr * 64 + col] = relu(acc[r] + b2v);
        }
    }
}

// ---------------------------------------------------------------------------
extern "C" void kernel_launch(void* const* d_in, const int* in_sizes, int n_in,
                              void* d_out, int out_size, void* d_ws, size_t ws_size,
                              hipStream_t stream)
{
    const float* u   = (const float*)d_in[0];
    const float* v   = (const float*)d_in[1];
    const float* ev  = (const float*)d_in[2];
    const int*   eiv = (const int*)d_in[3];
    const int*   eiu = (const int*)d_in[4];
    const float* gw1 = (const float*)d_in[5];   // 144 x 128
    const float* gb1 = (const float*)d_in[6];   // 128
    const float* gw2 = (const float*)d_in[7];   // 128 x 64
    const float* gb2 = (const float*)d_in[8];   // 64
    const float* fw1 = (const float*)d_in[9];   // 128 x 128
    const float* fb1 = (const float*)d_in[10];  // 128
    const float* fw2 = (const float*)d_in[11];  // 128 x 64
    const float* fb2 = (const float*)d_in[12];  // 64
    float* out = (float*)d_out;

    // workspace layout (agg and counts adjacent -> single memset); ~67.5 MB
    unsigned short* Up     = (unsigned short*)d_ws;                 // 50000x128 bf16
    unsigned short* Vp     = Up + (size_t)U_N * 128;                // 50000x128 bf16
    unsigned short* evs    = Vp + (size_t)V_N * 128;                // E x 16 bf16
    float*          agg    = (float*)(evs + (size_t)E_N * 16);      // 50000x64 f32
    int*            counts = (int*)(agg + (size_t)U_N * 64);        // NBINS (= cursor)
    unsigned int*   iuv_s  = (unsigned int*)(counts + NBINS);       // 800000
    unsigned short* W2f    = (unsigned short*)(iuv_s + E_N);        // 8192 bf16
    unsigned short* Wef    = W2f + 8192;                            // 4096 bf16
    unsigned short* F1f    = Wef + 4096;                            // 16384 bf16
    unsigned short* F2f    = F1f + 16384;                           // 8192 bf16
    int*            bsum   = (int*)(F2f + 8192);                    // NSCAN ints

    // one memset covers agg (zero init) + counts (hist init)
    hipMemsetAsync(agg, 0, ((size_t)U_N * 64 + NBINS) * sizeof(float), stream);

    dim3 blk(256);
    prep_kernel<<<dim3(2 * NB_PROJ + 1 + NB_HIST), blk, 0, stream>>>(
        eiu, counts, u, v, gw1, gw2, fw1, fw2, Up, Vp, W2f, Wef, F1f, F2f);
    scan_sums<<<dim3(NSCAN), blk, 0, stream>>>(counts, bsum);
    scan_bsum<<<dim3(1), dim3(512), 0, stream>>>(bsum);
    scan_apply<<<dim3(NSCAN), blk, 0, stream>>>(counts, bsum);
    permute_kernel<<<dim3(NB_HIST), blk, 0, stream>>>(
        eiu, eiv, ev, counts, iuv_s, evs);

    edge_kernel<<<dim3(E_N / 64), blk, 0, stream>>>(
        Up, Vp, evs, iuv_s, Wef, gb1, W2f, gb2, agg);
    node_kernel<<<dim3((U_N + 63) / 64), blk, 0, stream>>>(
        u, agg, F1f, fb1, F2f, fb2, out, U_N);
}